// Round 1
// baseline (2655.133 us; speedup 1.0000x reference)
//
#include <hip/hip_runtime.h>
#include <math.h>

#define SLEN 1024

__device__ __forceinline__ float sigf(float x) { return 1.0f / (1.0f + __expf(-x)); }

__device__ __forceinline__ float agent_ld(const float* p) {
  return __hip_atomic_load(p, __ATOMIC_RELAXED, __HIP_MEMORY_SCOPE_AGENT);
}
__device__ __forceinline__ void agent_st(float* p, float v) {
  __hip_atomic_store(p, v, __ATOMIC_RELAXED, __HIP_MEMORY_SCOPE_AGENT);
}
__device__ __forceinline__ bool is_sent(float f) { return __float_as_uint(f) == 0xFFFFFFFFu; }

// x[t, :] = emb[tokens[t, 63], :]   (only batch column 63 matters)
__global__ void embed_k(const int* __restrict__ tokens, const float* __restrict__ emb,
                        float* __restrict__ x) {
  const int t = blockIdx.x;
  const int tok = tokens[t * 64 + 63];
  const float4 v = ((const float4*)(emb + (size_t)tok * 512))[threadIdx.x];
  ((float4*)(x + (size_t)t * 512))[threadIdx.x] = v;
}

// One LSTM layer role. Block owns 8 hidden units = 32 gate rows of the fused
// weight matrix Wcat = [Wih | Whh] (4H x (EIN+HOUT)). Weights persist in VGPRs.
// Input vector concat[in_t ; h_{t-1}] staged in LDS each step.
// Thread (r2=tid>>6, c=tid&63): 4 gate rows x (C/64) cols; lane c reads float4
// slots {c, 64+c, 128+c, ...} -> conflict-free stride-16B ds_read_b128.
template<int HOUT, int EIN, bool POLL_IN>
__device__ void lstm_role(int ublk,
                          const float* __restrict__ Wih, const float* __restrict__ Whh,
                          const float* __restrict__ bih, const float* __restrict__ bhh,
                          const float* __restrict__ in_hist, float* __restrict__ hout) {
  constexpr int C     = EIN + HOUT;
  constexpr int SLOTS = C / 256;        // float4 slots per lane
  constexpr int XQ    = EIN / 4;        // float4-index boundary between Wih and Whh
  constexpr int EPN   = EIN / 512;      // input floats polled/loaded per thread
  constexpr int HPN   = (HOUT >= 512) ? (HOUT / 512) : 1;
  constexpr bool HGUARD = (HOUT < 512);

  __shared__ __align__(16) float in_lds[C];
  __shared__ float g_raw[32];

  const int tid = threadIdx.x;
  const int c   = tid & 63;
  const int r2  = tid >> 6;             // wave index, 0..7
  const int u0  = ublk * 8;

  // Persistent weight registers: 4 rows x SLOTS float4
  float4 wreg[4][SLOTS];
  #pragma unroll
  for (int rr = 0; rr < 4; ++rr) {
    const int lr = 4 * r2 + rr;         // local row 0..31
    const int gi = lr >> 3, ui = lr & 7;
    const size_t grow = (size_t)gi * HOUT + (size_t)(u0 + ui);
    const float4* wih4 = (const float4*)(Wih + grow * EIN);
    const float4* whh4 = (const float4*)(Whh + grow * HOUT);
    #pragma unroll
    for (int s = 0; s < SLOTS; ++s) {
      const int c4 = s * 64 + c;
      wreg[rr][s] = (c4 < XQ) ? wih4[c4] : whh4[c4 - XQ];
    }
  }

  float b0 = 0.f, b1 = 0.f, b2 = 0.f, b3 = 0.f, cst = 0.f;
  if (tid < 8) {
    b0 = bih[0*HOUT + u0 + tid] + bhh[0*HOUT + u0 + tid];
    b1 = bih[1*HOUT + u0 + tid] + bhh[1*HOUT + u0 + tid];
    b2 = bih[2*HOUT + u0 + tid] + bhh[2*HOUT + u0 + tid];
    b3 = bih[3*HOUT + u0 + tid] + bhh[3*HOUT + u0 + tid];
  }

  for (int t = 0; t < SLEN; ++t) {
    float ev[EPN];
    float hv[HPN];
    const float* esrc = in_hist + (size_t)t * EIN + EPN * tid;
    const float* hsrc = hout + (size_t)((t > 0 ? t : 1) - 1) * HOUT + HPN * tid;
    const bool hon   = (!HGUARD) || (tid * HPN < HOUT);
    const bool hneed = (t > 0) && hon;

    if constexpr (POLL_IN) {
      // combined poll: one round trip when both regions ready
      for (;;) {
        bool ok = true;
        #pragma unroll
        for (int i = 0; i < EPN; ++i) ev[i] = agent_ld(esrc + i);
        if (hneed) {
          #pragma unroll
          for (int i = 0; i < HPN; ++i) hv[i] = agent_ld(hsrc + i);
          #pragma unroll
          for (int i = 0; i < HPN; ++i) ok &= !is_sent(hv[i]);
        }
        #pragma unroll
        for (int i = 0; i < EPN; ++i) ok &= !is_sent(ev[i]);
        if (ok) break;
        __builtin_amdgcn_s_sleep(2);
      }
    } else {
      #pragma unroll
      for (int i = 0; i < EPN; ++i) ev[i] = esrc[i];   // x: plain cached loads
      if (hneed) {
        for (;;) {
          bool ok = true;
          #pragma unroll
          for (int i = 0; i < HPN; ++i) hv[i] = agent_ld(hsrc + i);
          #pragma unroll
          for (int i = 0; i < HPN; ++i) ok &= !is_sent(hv[i]);
          if (ok) break;
          __builtin_amdgcn_s_sleep(2);
        }
      }
    }

    #pragma unroll
    for (int i = 0; i < EPN; ++i) in_lds[EPN * tid + i] = ev[i];
    if (hon) {
      #pragma unroll
      for (int i = 0; i < HPN; ++i) in_lds[EIN + HPN * tid + i] = hneed ? hv[i] : 0.0f;
    }
    __syncthreads();

    float a0 = 0.f, a1 = 0.f, a2 = 0.f, a3 = 0.f;
    #pragma unroll
    for (int s = 0; s < SLOTS; ++s) {
      const float4 iv = ((const float4*)in_lds)[s * 64 + c];
      a0 += wreg[0][s].x*iv.x + wreg[0][s].y*iv.y + wreg[0][s].z*iv.z + wreg[0][s].w*iv.w;
      a1 += wreg[1][s].x*iv.x + wreg[1][s].y*iv.y + wreg[1][s].z*iv.z + wreg[1][s].w*iv.w;
      a2 += wreg[2][s].x*iv.x + wreg[2][s].y*iv.y + wreg[2][s].z*iv.z + wreg[2][s].w*iv.w;
      a3 += wreg[3][s].x*iv.x + wreg[3][s].y*iv.y + wreg[3][s].z*iv.z + wreg[3][s].w*iv.w;
    }
    #pragma unroll
    for (int off = 32; off > 0; off >>= 1) {
      a0 += __shfl_xor(a0, off);
      a1 += __shfl_xor(a1, off);
      a2 += __shfl_xor(a2, off);
      a3 += __shfl_xor(a3, off);
    }
    if (c == 0) {
      g_raw[4*r2 + 0] = a0; g_raw[4*r2 + 1] = a1;
      g_raw[4*r2 + 2] = a2; g_raw[4*r2 + 3] = a3;
    }
    __syncthreads();

    if (tid < 8) {
      const float I = sigf(g_raw[      tid] + b0);
      const float F = sigf(g_raw[ 8 +  tid] + b1);
      const float G = tanhf(g_raw[16 + tid] + b2);
      const float O = sigf(g_raw[24 + tid] + b3);
      cst = F * cst + I * G;
      agent_st(hout + (size_t)t * HOUT + u0 + tid, O * tanhf(cst));
    }
    __syncthreads();   // protect in_lds before next fill
  }
}

// out[t, :] = h2[t, :] @ Wlin.T + blin, 8 blocks, t strided by 8
__device__ void final_role(int fb, const float* __restrict__ h2,
                           const float* __restrict__ Wlin, const float* __restrict__ blin,
                           float* __restrict__ out) {
  const int tid = threadIdx.x;
  float wl[7];
  #pragma unroll
  for (int o = 0; o < 7; ++o) wl[o] = 0.f;
  if (tid < 256) {
    #pragma unroll
    for (int o = 0; o < 7; ++o) wl[o] = Wlin[o * 256 + tid];
  }
  __shared__ float red[4][7];
  for (int t = fb; t < SLEN; t += 8) {
    float h = 0.0f;
    if (tid < 256) {
      h = agent_ld(h2 + (size_t)t * 256 + tid);
      while (is_sent(h)) {
        __builtin_amdgcn_s_sleep(2);
        h = agent_ld(h2 + (size_t)t * 256 + tid);
      }
    }
    float p[7];
    #pragma unroll
    for (int o = 0; o < 7; ++o) p[o] = h * wl[o];
    #pragma unroll
    for (int off = 32; off > 0; off >>= 1) {
      #pragma unroll
      for (int o = 0; o < 7; ++o) p[o] += __shfl_xor(p[o], off);
    }
    const int w = tid >> 6;
    if (w < 4 && (tid & 63) == 0) {
      #pragma unroll
      for (int o = 0; o < 7; ++o) red[w][o] = p[o];
    }
    __syncthreads();
    if (tid == 0) {
      #pragma unroll
      for (int o = 0; o < 7; ++o)
        out[t * 7 + o] = red[0][o] + red[1][o] + red[2][o] + red[3][o] + blin[o];
    }
    __syncthreads();
  }
}

__global__ __launch_bounds__(512, 2) void pipe_k(
    const float* __restrict__ x,
    const float* __restrict__ Wih0, const float* __restrict__ Whh0,
    const float* __restrict__ bih0, const float* __restrict__ bhh0,
    const float* __restrict__ Wih1, const float* __restrict__ Whh1,
    const float* __restrict__ bih1, const float* __restrict__ bhh1,
    const float* __restrict__ Wih2, const float* __restrict__ Whh2,
    const float* __restrict__ bih2, const float* __restrict__ bhh2,
    const float* __restrict__ Wlin, const float* __restrict__ blin,
    float* __restrict__ h0, float* __restrict__ h1, float* __restrict__ h2,
    float* __restrict__ out) {
  const int b = blockIdx.x;
  if (b < 128) {
    lstm_role<1024, 512, false>(b, Wih0, Whh0, bih0, bhh0, x, h0);
  } else if (b < 192) {
    lstm_role<512, 1024, true>(b - 128, Wih1, Whh1, bih1, bhh1, h0, h1);
  } else if (b < 224) {
    lstm_role<256, 512, true>(b - 192, Wih2, Whh2, bih2, bhh2, h1, h2);
  } else {
    final_role(b - 224, h2, Wlin, blin, out);
  }
}

extern "C" void kernel_launch(void* const* d_in, const int* in_sizes, int n_in,
                              void* d_out, int out_size, void* d_ws, size_t ws_size,
                              hipStream_t stream) {
  const int*   tokens = (const int*)  d_in[0];
  const float* emb  = (const float*)d_in[1];
  const float* Wih0 = (const float*)d_in[2];
  const float* Whh0 = (const float*)d_in[3];
  const float* bih0 = (const float*)d_in[4];
  const float* bhh0 = (const float*)d_in[5];
  const float* Wih1 = (const float*)d_in[6];
  const float* Whh1 = (const float*)d_in[7];
  const float* bih1 = (const float*)d_in[8];
  const float* bhh1 = (const float*)d_in[9];
  const float* Wih2 = (const float*)d_in[10];
  const float* Whh2 = (const float*)d_in[11];
  const float* bih2 = (const float*)d_in[12];
  const float* bhh2 = (const float*)d_in[13];
  const float* Wlin = (const float*)d_in[14];
  const float* blin = (const float*)d_in[15];

  float* x  = (float*)d_ws;                      // 1024*512 f32 (2 MB)
  float* h0 = x  + (size_t)1024 * 512;           // 1024*1024 f32 (4 MB)
  float* h1 = h0 + (size_t)1024 * 1024;          // 1024*512  f32 (2 MB)
  float* h2 = h1 + (size_t)1024 * 512;           // 1024*256  f32 (1 MB)

  // Sentinel-fill the h history buffers (0xFFFFFFFF = NaN, never a valid h).
  hipMemsetAsync(h0, 0xFF,
                 ((size_t)1024*1024 + (size_t)1024*512 + (size_t)1024*256) * sizeof(float),
                 stream);
  embed_k<<<1024, 128, 0, stream>>>(tokens, emb, x);
  pipe_k<<<232, 512, 0, stream>>>(x, Wih0, Whh0, bih0, bhh0,
                                  Wih1, Whh1, bih1, bhh1,
                                  Wih2, Whh2, bih2, bhh2,
                                  Wlin, blin, h0, h1, h2, (float*)d_out);
}